// Round 15
// baseline (641.158 us; speedup 1.0000x reference)
//
#include <hip/hip_runtime.h>
#include <hip/hip_bf16.h>
#include <math.h>

#define NODES 50000
#define EDGES 800000
#define EP    850000      // EDGES + NODES self loops
#define INCH  64
#define HIDD  96
#define NHEAD 4
#define CHD   24
#define NLAY  4
#define NGRF  1024
#define BNEPS 1e-5f
#define NB    49          // ceil(NODES/1024)

__device__ __forceinline__ float elu1(float v) { return v > 0.f ? v : __expf(v) - 1.f; }

__device__ __forceinline__ unsigned short f2bf(float f) {   // RNE, matches HW
    unsigned u = __float_as_uint(f);
    return (unsigned short)((u + 0x7fffu + ((u >> 16) & 1u)) >> 16);
}

__device__ __forceinline__ float rl_f(float v, int l) {     // readlane broadcast (uniform l)
    return __int_as_float(__builtin_amdgcn_readlane(__float_as_int(v), l));
}

__device__ __forceinline__ float bnorm(float a, const float* __restrict__ bg,
                                       const float* __restrict__ rm, const float* __restrict__ rv,
                                       const float* __restrict__ gamma, const float* __restrict__ beta,
                                       int ch) {
    float hn = a + bg[ch];
    return (hn - rm[ch]) / sqrtf(rv[ch] + BNEPS) * gamma[ch] + beta[ch];
}

__device__ __forceinline__ void edge_sd(int e, const int* __restrict__ S,
                                        const int* __restrict__ D, int& s, int& d) {
    if (e < EDGES) { s = S[e]; d = D[e]; } else { s = e - EDGES; d = s; }
}

// ---------------- CSR build (once per call; graph is layer-invariant) ----------------

__global__ __launch_bounds__(256) void k_count(const int* __restrict__ S, const int* __restrict__ D,
                                               int* __restrict__ cnt) {
    int e = blockIdx.x * blockDim.x + threadIdx.x;
    if (e >= EP) return;
    int s, d; edge_sd(e, S, D, s, d);
    atomicAdd(&cnt[d], 1);
}

__global__ __launch_bounds__(1024) void k_scan1(const int* __restrict__ cnt,
                                                int* __restrict__ off, int* __restrict__ bsum) {
    __shared__ int sd[1024];
    int t = threadIdx.x;
    int i = blockIdx.x * 1024 + t;
    int v = (i < NODES) ? cnt[i] : 0;
    sd[t] = v; __syncthreads();
    for (int o = 1; o < 1024; o <<= 1) {
        int tv = (t >= o) ? sd[t - o] : 0;
        __syncthreads();
        sd[t] += tv; __syncthreads();
    }
    if (i < NODES) off[i] = sd[t] - v;           // exclusive within block
    if (t == 1023) bsum[blockIdx.x] = sd[1023];
}

// merged scan2+scan3: each block redundantly prefixes bsum (49 adds); off[N]=EP constant.
__global__ __launch_bounds__(1024) void k_scan3m(int* __restrict__ off, const int* __restrict__ bsum,
                                                 int* __restrict__ cursor) {
    int carry = 0;
    for (int b = 0; b < blockIdx.x; ++b) carry += bsum[b];   // uniform s_loads
    int i = blockIdx.x * 1024 + threadIdx.x;
    if (i < NODES) {
        int o = off[i] + carry;
        off[i] = o;
        cursor[i] = o;
    }
    if (i == 0) off[NODES] = EP;
}

__global__ __launch_bounds__(256) void k_scatter(const int* __restrict__ S, const int* __restrict__ D,
                                                 int* __restrict__ cursor, int* __restrict__ csr_src) {
    int e = blockIdx.x * blockDim.x + threadIdx.x;
    if (e >= EP) return;
    int s, d; edge_sd(e, S, D, s, d);
    int pos = atomicAdd(&cursor[d], 1);
    csr_src[pos] = s;
}

// ---------------- fused input proj + layer-0 proj (global/L2 h exchange) ----------------
// Also zeros `pooled` (runs before any k_edge in stream order) -> one fewer memset dispatch.

__global__ __launch_bounds__(256) void k_in_proj_proj(const float* __restrict__ x,
                                                      const float* __restrict__ W_in,
                                                      const float* __restrict__ b_in,
                                                      const float* __restrict__ Wg0,
                                                      const float* __restrict__ asrc,
                                                      const float* __restrict__ adst,
                                                      float* __restrict__ h,
                                                      unsigned* __restrict__ hpb,
                                                      float* __restrict__ as_,
                                                      float* __restrict__ ad_,
                                                      float* __restrict__ pooled_all) {
    __shared__ float Wl[HIDD * HIDD];       // 36 KB: W_in (first 24 KB) then Wg0
    int tid = threadIdx.x;
    // zero pooled (grid-stride; completes before kernel end -> before k_edge)
    for (size_t i = (size_t)blockIdx.x * 256 + tid; i < (size_t)NLAY * NGRF * HIDD;
         i += (size_t)gridDim.x * 256)
        pooled_all[i] = 0.f;
    for (int i = tid; i < INCH * HIDD / 4; i += 256)
        ((float4*)Wl)[i] = ((const float4*)W_in)[i];
    __syncthreads();

    int lane = tid & 63;
    int node = blockIdx.x * 64 + lane;
    bool valid = node < NODES;
    int head = tid >> 6;                    // cgroup == head (wave-uniform)
    int cbase = head * CHD;

    // ---- stage 1: in_proj -> global h ----
    {
        const float* __restrict__ xr = x + (size_t)node * INCH;
        float acc[CHD];
#pragma unroll
        for (int j = 0; j < CHD; ++j) acc[j] = b_in[cbase + j];
        if (valid) {
            for (int k0 = 0; k0 < INCH; k0 += 4) {
                float4 xv = *(const float4*)(xr + k0);
                const float xvv[4] = {xv.x, xv.y, xv.z, xv.w};
#pragma unroll
                for (int kk = 0; kk < 4; ++kk) {
#pragma unroll
                    for (int j4 = 0; j4 < CHD; j4 += 4) {
                        float4 wv = *(const float4*)(&Wl[(k0 + kk) * HIDD + cbase + j4]);
                        acc[j4 + 0] = fmaf(xvv[kk], wv.x, acc[j4 + 0]);
                        acc[j4 + 1] = fmaf(xvv[kk], wv.y, acc[j4 + 1]);
                        acc[j4 + 2] = fmaf(xvv[kk], wv.z, acc[j4 + 2]);
                        acc[j4 + 3] = fmaf(xvv[kk], wv.w, acc[j4 + 3]);
                    }
                }
            }
            float* hrow = h + (size_t)node * HIDD + cbase;
#pragma unroll
            for (int j = 0; j < CHD; ++j) hrow[j] = elu1(acc[j]);
        }
    }
    __syncthreads();                        // h writes drained (vmcnt) + visible via L2
    // ---- restage Wg0 ----
    for (int i = tid; i < HIDD * HIDD / 4; i += 256)
        ((float4*)Wl)[i] = ((const float4*)Wg0)[i];
    __syncthreads();

    // ---- stage 2: proj from global h (L1/L2-hot) ----
    const float* __restrict__ hr = h + (size_t)node * HIDD;
    float acc[CHD] = {};
    for (int k0 = 0; k0 < HIDD; k0 += 4) {
        float4 hv = *(const float4*)(hr + k0);
        const float hvv[4] = {hv.x, hv.y, hv.z, hv.w};
#pragma unroll
        for (int kk = 0; kk < 4; ++kk) {
#pragma unroll
            for (int j4 = 0; j4 < CHD; j4 += 4) {
                float4 wv = *(const float4*)(&Wl[(k0 + kk) * HIDD + cbase + j4]);
                acc[j4 + 0] = fmaf(hvv[kk], wv.x, acc[j4 + 0]);
                acc[j4 + 1] = fmaf(hvv[kk], wv.y, acc[j4 + 1]);
                acc[j4 + 2] = fmaf(hvv[kk], wv.z, acc[j4 + 2]);
                acc[j4 + 3] = fmaf(hvv[kk], wv.w, acc[j4 + 3]);
            }
        }
    }
    if (valid) {
        unsigned* orow = hpb + (size_t)node * (HIDD / 2) + cbase / 2;
#pragma unroll
        for (int j = 0; j < CHD; j += 2)
            orow[j / 2] = (unsigned)f2bf(acc[j]) | ((unsigned)f2bf(acc[j + 1]) << 16);
        const float* __restrict__ s = asrc + head * CHD;
        const float* __restrict__ d = adst + head * CHD;
        float sa = 0.f, da = 0.f;
#pragma unroll
        for (int j = 0; j < CHD; ++j) { sa = fmaf(acc[j], s[j], sa); da = fmaf(acc[j], d[j], da); }
        as_[node * NHEAD + head] = sa;
        ad_[node * NHEAD + head] = da;
    }
}

// ---------------- per-layer proj (layers 1..3) ----------------

__global__ __launch_bounds__(256) void k_proj(const float* __restrict__ h,
                                              const float* __restrict__ W,
                                              const float* __restrict__ asrc,
                                              const float* __restrict__ adst,
                                              unsigned* __restrict__ hpb,   // [N][48] packed bf16x2
                                              float* __restrict__ as_,
                                              float* __restrict__ ad_) {
    __shared__ float Wl[HIDD * HIDD];   // 36 KB
    int tid = threadIdx.x;
    for (int i = tid; i < HIDD * HIDD / 4; i += 256)
        ((float4*)Wl)[i] = ((const float4*)W)[i];
    __syncthreads();

    int node = blockIdx.x * 64 + (tid & 63);
    if (node >= NODES) return;
    int head = tid >> 6;                 // 0..3 (wave-uniform)
    int cbase = head * CHD;
    const float* __restrict__ hr = h + (size_t)node * HIDD;

    float acc[CHD] = {};
    for (int k0 = 0; k0 < HIDD; k0 += 4) {
        float4 hv = *(const float4*)(hr + k0);
        const float hvv[4] = {hv.x, hv.y, hv.z, hv.w};
#pragma unroll
        for (int kk = 0; kk < 4; ++kk) {
#pragma unroll
            for (int j4 = 0; j4 < CHD; j4 += 4) {
                float4 wv = *(const float4*)(&Wl[(k0 + kk) * HIDD + cbase + j4]);
                acc[j4 + 0] = fmaf(hvv[kk], wv.x, acc[j4 + 0]);
                acc[j4 + 1] = fmaf(hvv[kk], wv.y, acc[j4 + 1]);
                acc[j4 + 2] = fmaf(hvv[kk], wv.z, acc[j4 + 2]);
                acc[j4 + 3] = fmaf(hvv[kk], wv.w, acc[j4 + 3]);
            }
        }
    }
    unsigned* orow = hpb + (size_t)node * (HIDD / 2) + cbase / 2;
#pragma unroll
    for (int j = 0; j < CHD; j += 2)
        orow[j / 2] = (unsigned)f2bf(acc[j]) | ((unsigned)f2bf(acc[j + 1]) << 16);

    const float* __restrict__ s = asrc + head * CHD;
    const float* __restrict__ d = adst + head * CHD;
    float sa = 0.f, da = 0.f;
#pragma unroll
    for (int j = 0; j < CHD; ++j) { sa = fmaf(acc[j], s[j], sa); da = fmaf(acc[j], d[j], da); }
    as_[node * NHEAD + head] = sa;
    ad_[node * NHEAD + head] = da;
}

// ---------------- fused edge phase: 2 nodes/wave, split load-issue / FMA phases ----------------
// alpha = exp(leaky(as+ad)) / z (max-sub cancels in p/z; |ev| << 88, no overflow).
// Per chunk pair: ALL guarded gathers (up to 32) are issued into register arrays BEFORE
// any FMA consumes them -> gather latencies overlap instead of serializing per-branch.

__global__ __launch_bounds__(256) void k_edge(const int* __restrict__ off,
                                              const int* __restrict__ csr,
                                              const float* __restrict__ as_,
                                              const float* __restrict__ ad_,
                                              const unsigned* __restrict__ hpb,
                                              const float* __restrict__ bg,
                                              const float* __restrict__ gamma,
                                              const float* __restrict__ beta,
                                              const float* __restrict__ rm,
                                              const float* __restrict__ rv,
                                              float* __restrict__ h,
                                              const int* __restrict__ batch,
                                              float* __restrict__ pooled) {
    __shared__ float plds[512];                     // per wave: 128 floats (2 nodes x 64)
    int tid = threadIdx.x;
    int lane = tid & 63;
    int n0 = __builtin_amdgcn_readfirstlane(blockIdx.x * 8 + (tid >> 6) * 2);  // exact grid
    int n1 = n0 + 1;
    int beg0 = off[n0], end0 = off[n0 + 1], end1 = off[n0 + 2];
    int beg1 = end0;                                // consecutive nodes share the boundary

    int hd = lane & 3, slot = lane >> 2;            // alpha role: edge slot x head
    float adv0 = ad_[n0 * NHEAD + hd];
    float adv1 = ad_[n1 * NHEAD + hd];
    const int hh = (lane < 48) ? (lane / 12) : 0;   // gather role: head of channel pair
    const bool gl = (lane < 48);
    const int wb = (tid & 192) * 2;                 // wave's plds region (w*128)

    float a00 = 0.f, a01 = 0.f, a10 = 0.f, a11 = 0.f, zA = 0.f, zB = 0.f;
    int ca = beg0, cb = beg1;
    while (ca < end0 || cb < end1) {
        int cntA = min(16, end0 - ca);              // wave-uniform chunk fills
        int cntB = min(16, end1 - cb);
        int sA = 0, sB = 0;
        if (cntA > 0) {
            int i = ca + slot, ii = min(i, end0 - 1);
            sA = csr[ii];
            float ev = as_[sA * NHEAD + hd] + adv0;
            ev = ev > 0.f ? ev : 0.2f * ev;
            float p = (i < end0) ? __expf(ev) : 0.f;
            zA += p;
            plds[wb + lane] = p;
        }
        if (cntB > 0) {
            int i = cb + slot, ii = min(i, end1 - 1);
            sB = csr[ii];
            float ev = as_[sB * NHEAD + hd] + adv1;
            ev = ev > 0.f ? ev : 0.2f * ev;
            float p = (i < end1) ? __expf(ev) : 0.f;
            zB += p;
            plds[wb + 64 + lane] = p;
        }
        // ---- load-issue phase: up to 32 gathers in flight ----
        unsigned uA[16], uB[16];
        float alA[16], alB[16];
#pragma unroll
        for (int j = 0; j < 16; ++j) {
            if (j < cntA) {
                int sv = __builtin_amdgcn_readlane(sA, j * 4);
                alA[j] = plds[wb + j * 4 + hh];
                if (gl) uA[j] = (hpb + (size_t)sv * (HIDD / 2))[lane];
            }
        }
#pragma unroll
        for (int j = 0; j < 16; ++j) {
            if (j < cntB) {
                int sv = __builtin_amdgcn_readlane(sB, j * 4);
                alB[j] = plds[wb + 64 + j * 4 + hh];
                if (gl) uB[j] = (hpb + (size_t)sv * (HIDD / 2))[lane];
            }
        }
        // ---- FMA phase ----
#pragma unroll
        for (int j = 0; j < 16; ++j) {
            if (j < cntA && gl) {
                a00 = fmaf(__uint_as_float(uA[j] << 16),         alA[j], a00);
                a01 = fmaf(__uint_as_float(uA[j] & 0xffff0000u), alA[j], a01);
            }
        }
#pragma unroll
        for (int j = 0; j < 16; ++j) {
            if (j < cntB && gl) {
                a10 = fmaf(__uint_as_float(uB[j] << 16),         alB[j], a10);
                a11 = fmaf(__uint_as_float(uB[j] & 0xffff0000u), alB[j], a11);
            }
        }
        if (cntA > 0) ca += 16;
        if (cntB > 0) cb += 16;
    }
    // z totals per head for both nodes
#pragma unroll
    for (int o = 4; o < 64; o <<= 1) { zA += __shfl_xor(zA, o); zB += __shfl_xor(zB, o); }
    float za0 = rl_f(zA, 0), za1 = rl_f(zA, 1), za2 = rl_f(zA, 2), za3 = rl_f(zA, 3);
    float zb0 = rl_f(zB, 0), zb1 = rl_f(zB, 1), zb2 = rl_f(zB, 2), zb3 = rl_f(zB, 3);
    float zAl = (hh & 1) ? za1 : za0, zAh = (hh & 1) ? za3 : za2;
    float zBl = (hh & 1) ? zb1 : zb0, zBh = (hh & 1) ? zb3 : zb2;
    float zhA = (hh & 2) ? zAh : zAl;
    float zhB = (hh & 2) ? zBh : zBl;

    int g0 = batch[n0], g1 = batch[n1];             // uniform (s_load)
    if (gl) {
        float izA = 1.f / zhA, izB = 1.f / zhB;     // z > 0 guaranteed (self-loop)
        a00 *= izA; a01 *= izA; a10 *= izB; a11 *= izB;
        int ch0 = 2 * lane, ch1 = ch0 + 1;
        float hn00 = bnorm(a00, bg, rm, rv, gamma, beta, ch0);
        float hn01 = bnorm(a01, bg, rm, rv, gamma, beta, ch1);
        float hn10 = bnorm(a10, bg, rm, rv, gamma, beta, ch0);
        float hn11 = bnorm(a11, bg, rm, rv, gamma, beta, ch1);
        float2 hv0 = *(float2*)(h + (size_t)n0 * HIDD + ch0);
        float2 hv1 = *(float2*)(h + (size_t)n1 * HIDD + ch0);
        hv0.x += elu1(hn00); hv0.y += elu1(hn01);
        hv1.x += elu1(hn10); hv1.y += elu1(hn11);
        *(float2*)(h + (size_t)n0 * HIDD + ch0) = hv0;
        *(float2*)(h + (size_t)n1 * HIDD + ch0) = hv1;
        if (g0 == g1) {                             // merged pooled atomics (common: sorted batch)
            atomicAdd(&pooled[g0 * HIDD + ch0], hv0.x + hv1.x);
            atomicAdd(&pooled[g0 * HIDD + ch1], hv0.y + hv1.y);
        } else {
            atomicAdd(&pooled[g0 * HIDD + ch0], hv0.x);
            atomicAdd(&pooled[g0 * HIDD + ch1], hv0.y);
            atomicAdd(&pooled[g1 * HIDD + ch0], hv1.x);
            atomicAdd(&pooled[g1 * HIDD + ch1], hv1.y);
        }
    }
}

// ---------------- per-graph MLP head ----------------

__global__ __launch_bounds__(128) void k_head(const float* __restrict__ pooled,
                                              const float* __restrict__ Wjk, const float* __restrict__ bjk,
                                              const float* __restrict__ Wh1, const float* __restrict__ bh1,
                                              const float* __restrict__ Wh2, const float* __restrict__ bh2,
                                              float* __restrict__ out) {
    __shared__ float pin[NLAY * HIDD];
    __shared__ float z1[HIDD];
    __shared__ float z2[HIDD];
    int g = blockIdx.x, tid = threadIdx.x;
    for (int idx = tid; idx < NLAY * HIDD; idx += blockDim.x) {
        int l = idx / HIDD, c = idx % HIDD;
        pin[idx] = pooled[(size_t)l * NGRF * HIDD + (size_t)g * HIDD + c];
    }
    __syncthreads();
    for (int c = tid; c < HIDD; c += blockDim.x) {
        float a = bjk[c];
#pragma unroll 8
        for (int k = 0; k < NLAY * HIDD; ++k) a = fmaf(pin[k], Wjk[k * HIDD + c], a);
        z1[c] = elu1(a);
    }
    __syncthreads();
    for (int c = tid; c < HIDD; c += blockDim.x) {
        float a = bh1[c];
#pragma unroll 8
        for (int k = 0; k < HIDD; ++k) a = fmaf(z1[k], Wh1[k * HIDD + c], a);
        z2[c] = fmaxf(a, 0.f);
    }
    __syncthreads();
    if (tid < 64) {
        float a = 0.f;
        for (int k = tid; k < HIDD; k += 64) a = fmaf(z2[k], Wh2[k], a);
#pragma unroll
        for (int o = 32; o > 0; o >>= 1) a += __shfl_down(a, o);
        if (tid == 0) out[g] = a + bh2[0];
    }
}

extern "C" void kernel_launch(void* const* d_in, const int* in_sizes, int n_in,
                              void* d_out, int out_size, void* d_ws, size_t ws_size,
                              hipStream_t stream) {
    const float* x     = (const float*)d_in[0];
    const int*   ei    = (const int*)d_in[1];
    const int*   batch = (const int*)d_in[2];
    const float* W_in  = (const float*)d_in[3];
    const float* b_in  = (const float*)d_in[4];
    const float* Wg    = (const float*)d_in[5];
    const float* att_s = (const float*)d_in[6];
    const float* att_d = (const float*)d_in[7];
    const float* bg    = (const float*)d_in[8];
    const float* gamma = (const float*)d_in[9];
    const float* beta  = (const float*)d_in[10];
    const float* rm    = (const float*)d_in[11];
    const float* rv    = (const float*)d_in[12];
    const float* Wjk   = (const float*)d_in[13];
    const float* bjk   = (const float*)d_in[14];
    const float* Wh1   = (const float*)d_in[15];
    const float* bh1   = (const float*)d_in[16];
    const float* Wh2   = (const float*)d_in[17];
    const float* bh2   = (const float*)d_in[18];
    float* out = (float*)d_out;

    const int* S = ei;
    const int* Dd = ei + EDGES;

    // workspace layout
    float* ws = (float*)d_ws;
    float*    h      = ws;                               // N*96 f32
    float*    as_    = h    + (size_t)NODES * HIDD;      // N*4
    float*    ad_    = as_  + (size_t)NODES * NHEAD;     // N*4
    float*    pooled = ad_  + (size_t)NODES * NHEAD;     // L*G*96
    unsigned* hpb    = (unsigned*)(pooled + (size_t)NLAY * NGRF * HIDD); // N*48 (bf16x2)
    int*      off    = (int*)(hpb + (size_t)NODES * (HIDD / 2));  // N+2
    int*      cursor = off    + NODES + 2;               // N
    int*      csr    = cursor + NODES;                   // EP
    int*      cnt    = csr    + EP;                      // N
    int*      bsum   = cnt    + NODES;                   // NB

    hipMemsetAsync(cnt, 0, sizeof(int) * NODES, stream);

    const int TB = 256;
    int gE    = (EP + TB - 1) / TB;
    int gTile = (NODES + 63) / 64;    // 782 blocks, 64 nodes each
    int gEdge = NODES / 8;            // 6250 (exact: 8 nodes/block, 2 per wave)

    // CSR build (graph is identical across layers)
    k_count<<<gE, TB, 0, stream>>>(S, Dd, cnt);
    k_scan1<<<NB, 1024, 0, stream>>>(cnt, off, bsum);
    k_scan3m<<<NB, 1024, 0, stream>>>(off, bsum, cursor);
    k_scatter<<<gE, TB, 0, stream>>>(S, Dd, cursor, csr);

    // layer 0: fused input-proj + proj (also zeros pooled)
    k_in_proj_proj<<<gTile, TB, 0, stream>>>(x, W_in, b_in, Wg, att_s, att_d,
                                             h, hpb, as_, ad_, pooled);
    k_edge<<<gEdge, TB, 0, stream>>>(off, csr, as_, ad_, hpb,
                                     bg, gamma, beta, rm, rv, h, batch, pooled);

    for (int i = 1; i < NLAY; ++i) {
        k_proj<<<gTile, TB, 0, stream>>>(h, Wg + (size_t)i * HIDD * HIDD,
                                         att_s + i * NHEAD * CHD, att_d + i * NHEAD * CHD,
                                         hpb, as_, ad_);
        k_edge<<<gEdge, TB, 0, stream>>>(off, csr, as_, ad_, hpb,
                                         bg + i * HIDD, gamma + i * HIDD, beta + i * HIDD,
                                         rm + i * HIDD, rv + i * HIDD, h, batch,
                                         pooled + (size_t)i * NGRF * HIDD);
    }

    k_head<<<NGRF, 128, 0, stream>>>(pooled, Wjk, bjk, Wh1, bh1, Wh2, bh2, out);
}

// Round 16
// 546.924 us; speedup vs baseline: 1.1723x; 1.1723x over previous
//
#include <hip/hip_runtime.h>
#include <hip/hip_bf16.h>
#include <math.h>

#define NODES 50000
#define EDGES 800000
#define EP    850000      // EDGES + NODES self loops
#define INCH  64
#define HIDD  96
#define NHEAD 4
#define CHD   24
#define NLAY  4
#define NGRF  1024
#define BNEPS 1e-5f
#define NB    49          // ceil(NODES/1024)

__device__ __forceinline__ float elu1(float v) { return v > 0.f ? v : __expf(v) - 1.f; }

__device__ __forceinline__ unsigned short f2bf(float f) {   // RNE, matches HW
    unsigned u = __float_as_uint(f);
    return (unsigned short)((u + 0x7fffu + ((u >> 16) & 1u)) >> 16);
}

__device__ __forceinline__ float rl_f(float v, int l) {     // readlane broadcast (uniform l)
    return __int_as_float(__builtin_amdgcn_readlane(__float_as_int(v), l));
}

__device__ __forceinline__ float bnorm(float a, const float* __restrict__ bg,
                                       const float* __restrict__ rm, const float* __restrict__ rv,
                                       const float* __restrict__ gamma, const float* __restrict__ beta,
                                       int ch) {
    float hn = a + bg[ch];
    return (hn - rm[ch]) / sqrtf(rv[ch] + BNEPS) * gamma[ch] + beta[ch];
}

__device__ __forceinline__ void edge_sd(int e, const int* __restrict__ S,
                                        const int* __restrict__ D, int& s, int& d) {
    if (e < EDGES) { s = S[e]; d = D[e]; } else { s = e - EDGES; d = s; }
}

// ---------------- CSR build (once per call; graph is layer-invariant) ----------------

__global__ __launch_bounds__(256) void k_count(const int* __restrict__ S, const int* __restrict__ D,
                                               int* __restrict__ cnt) {
    int e = blockIdx.x * blockDim.x + threadIdx.x;
    if (e >= EP) return;
    int s, d; edge_sd(e, S, D, s, d);
    atomicAdd(&cnt[d], 1);
}

__global__ __launch_bounds__(1024) void k_scan1(const int* __restrict__ cnt,
                                                int* __restrict__ off, int* __restrict__ bsum) {
    __shared__ int sd[1024];
    int t = threadIdx.x;
    int i = blockIdx.x * 1024 + t;
    int v = (i < NODES) ? cnt[i] : 0;
    sd[t] = v; __syncthreads();
    for (int o = 1; o < 1024; o <<= 1) {
        int tv = (t >= o) ? sd[t - o] : 0;
        __syncthreads();
        sd[t] += tv; __syncthreads();
    }
    if (i < NODES) off[i] = sd[t] - v;           // exclusive within block
    if (t == 1023) bsum[blockIdx.x] = sd[1023];
}

// merged scan2+scan3: each block redundantly prefixes bsum (49 adds); off[N]=EP constant.
__global__ __launch_bounds__(1024) void k_scan3m(int* __restrict__ off, const int* __restrict__ bsum,
                                                 int* __restrict__ cursor) {
    int carry = 0;
    for (int b = 0; b < blockIdx.x; ++b) carry += bsum[b];   // uniform s_loads
    int i = blockIdx.x * 1024 + threadIdx.x;
    if (i < NODES) {
        int o = off[i] + carry;
        off[i] = o;
        cursor[i] = o;
    }
    if (i == 0) off[NODES] = EP;
}

__global__ __launch_bounds__(256) void k_scatter(const int* __restrict__ S, const int* __restrict__ D,
                                                 int* __restrict__ cursor, int* __restrict__ csr_src) {
    int e = blockIdx.x * blockDim.x + threadIdx.x;
    if (e >= EP) return;
    int s, d; edge_sd(e, S, D, s, d);
    int pos = atomicAdd(&cursor[d], 1);
    csr_src[pos] = s;
}

// ---------------- fused input proj + layer-0 proj (global/L2 h exchange) ----------------
// Also zeros `pooled` (runs before any k_edge in stream order) -> one fewer memset dispatch.

__global__ __launch_bounds__(256) void k_in_proj_proj(const float* __restrict__ x,
                                                      const float* __restrict__ W_in,
                                                      const float* __restrict__ b_in,
                                                      const float* __restrict__ Wg0,
                                                      const float* __restrict__ asrc,
                                                      const float* __restrict__ adst,
                                                      float* __restrict__ h,
                                                      unsigned* __restrict__ hpb,
                                                      float* __restrict__ as_,
                                                      float* __restrict__ ad_,
                                                      float* __restrict__ pooled_all) {
    __shared__ float Wl[HIDD * HIDD];       // 36 KB: W_in (first 24 KB) then Wg0
    int tid = threadIdx.x;
    // zero pooled (grid-stride; completes before kernel end -> before k_edge)
    for (size_t i = (size_t)blockIdx.x * 256 + tid; i < (size_t)NLAY * NGRF * HIDD;
         i += (size_t)gridDim.x * 256)
        pooled_all[i] = 0.f;
    for (int i = tid; i < INCH * HIDD / 4; i += 256)
        ((float4*)Wl)[i] = ((const float4*)W_in)[i];
    __syncthreads();

    int lane = tid & 63;
    int node = blockIdx.x * 64 + lane;
    bool valid = node < NODES;
    int head = tid >> 6;                    // cgroup == head (wave-uniform)
    int cbase = head * CHD;

    // ---- stage 1: in_proj -> global h ----
    {
        const float* __restrict__ xr = x + (size_t)node * INCH;
        float acc[CHD];
#pragma unroll
        for (int j = 0; j < CHD; ++j) acc[j] = b_in[cbase + j];
        if (valid) {
            for (int k0 = 0; k0 < INCH; k0 += 4) {
                float4 xv = *(const float4*)(xr + k0);
                const float xvv[4] = {xv.x, xv.y, xv.z, xv.w};
#pragma unroll
                for (int kk = 0; kk < 4; ++kk) {
#pragma unroll
                    for (int j4 = 0; j4 < CHD; j4 += 4) {
                        float4 wv = *(const float4*)(&Wl[(k0 + kk) * HIDD + cbase + j4]);
                        acc[j4 + 0] = fmaf(xvv[kk], wv.x, acc[j4 + 0]);
                        acc[j4 + 1] = fmaf(xvv[kk], wv.y, acc[j4 + 1]);
                        acc[j4 + 2] = fmaf(xvv[kk], wv.z, acc[j4 + 2]);
                        acc[j4 + 3] = fmaf(xvv[kk], wv.w, acc[j4 + 3]);
                    }
                }
            }
            float* hrow = h + (size_t)node * HIDD + cbase;
#pragma unroll
            for (int j = 0; j < CHD; ++j) hrow[j] = elu1(acc[j]);
        }
    }
    __syncthreads();                        // h writes drained (vmcnt) + visible via L2
    // ---- restage Wg0 ----
    for (int i = tid; i < HIDD * HIDD / 4; i += 256)
        ((float4*)Wl)[i] = ((const float4*)Wg0)[i];
    __syncthreads();

    // ---- stage 2: proj from global h (L1/L2-hot) ----
    const float* __restrict__ hr = h + (size_t)node * HIDD;
    float acc[CHD] = {};
    for (int k0 = 0; k0 < HIDD; k0 += 4) {
        float4 hv = *(const float4*)(hr + k0);
        const float hvv[4] = {hv.x, hv.y, hv.z, hv.w};
#pragma unroll
        for (int kk = 0; kk < 4; ++kk) {
#pragma unroll
            for (int j4 = 0; j4 < CHD; j4 += 4) {
                float4 wv = *(const float4*)(&Wl[(k0 + kk) * HIDD + cbase + j4]);
                acc[j4 + 0] = fmaf(hvv[kk], wv.x, acc[j4 + 0]);
                acc[j4 + 1] = fmaf(hvv[kk], wv.y, acc[j4 + 1]);
                acc[j4 + 2] = fmaf(hvv[kk], wv.z, acc[j4 + 2]);
                acc[j4 + 3] = fmaf(hvv[kk], wv.w, acc[j4 + 3]);
            }
        }
    }
    if (valid) {
        unsigned* orow = hpb + (size_t)node * (HIDD / 2) + cbase / 2;
#pragma unroll
        for (int j = 0; j < CHD; j += 2)
            orow[j / 2] = (unsigned)f2bf(acc[j]) | ((unsigned)f2bf(acc[j + 1]) << 16);
        const float* __restrict__ s = asrc + head * CHD;
        const float* __restrict__ d = adst + head * CHD;
        float sa = 0.f, da = 0.f;
#pragma unroll
        for (int j = 0; j < CHD; ++j) { sa = fmaf(acc[j], s[j], sa); da = fmaf(acc[j], d[j], da); }
        as_[node * NHEAD + head] = sa;
        ad_[node * NHEAD + head] = da;
    }
}

// ---------------- per-layer proj (layers 1..3) ----------------

__global__ __launch_bounds__(256) void k_proj(const float* __restrict__ h,
                                              const float* __restrict__ W,
                                              const float* __restrict__ asrc,
                                              const float* __restrict__ adst,
                                              unsigned* __restrict__ hpb,   // [N][48] packed bf16x2
                                              float* __restrict__ as_,
                                              float* __restrict__ ad_) {
    __shared__ float Wl[HIDD * HIDD];   // 36 KB
    int tid = threadIdx.x;
    for (int i = tid; i < HIDD * HIDD / 4; i += 256)
        ((float4*)Wl)[i] = ((const float4*)W)[i];
    __syncthreads();

    int node = blockIdx.x * 64 + (tid & 63);
    if (node >= NODES) return;
    int head = tid >> 6;                 // 0..3 (wave-uniform)
    int cbase = head * CHD;
    const float* __restrict__ hr = h + (size_t)node * HIDD;

    float acc[CHD] = {};
    for (int k0 = 0; k0 < HIDD; k0 += 4) {
        float4 hv = *(const float4*)(hr + k0);
        const float hvv[4] = {hv.x, hv.y, hv.z, hv.w};
#pragma unroll
        for (int kk = 0; kk < 4; ++kk) {
#pragma unroll
            for (int j4 = 0; j4 < CHD; j4 += 4) {
                float4 wv = *(const float4*)(&Wl[(k0 + kk) * HIDD + cbase + j4]);
                acc[j4 + 0] = fmaf(hvv[kk], wv.x, acc[j4 + 0]);
                acc[j4 + 1] = fmaf(hvv[kk], wv.y, acc[j4 + 1]);
                acc[j4 + 2] = fmaf(hvv[kk], wv.z, acc[j4 + 2]);
                acc[j4 + 3] = fmaf(hvv[kk], wv.w, acc[j4 + 3]);
            }
        }
    }
    unsigned* orow = hpb + (size_t)node * (HIDD / 2) + cbase / 2;
#pragma unroll
    for (int j = 0; j < CHD; j += 2)
        orow[j / 2] = (unsigned)f2bf(acc[j]) | ((unsigned)f2bf(acc[j + 1]) << 16);

    const float* __restrict__ s = asrc + head * CHD;
    const float* __restrict__ d = adst + head * CHD;
    float sa = 0.f, da = 0.f;
#pragma unroll
    for (int j = 0; j < CHD; ++j) { sa = fmaf(acc[j], s[j], sa); da = fmaf(acc[j], d[j], da); }
    as_[node * NHEAD + head] = sa;
    ad_[node * NHEAD + head] = da;
}

// ---------------- fused edge phase: 2 nodes per wave, uniform-guarded chunks ----------------
// alpha = exp(leaky(as+ad)) / z (max-sub cancels in p/z; |ev| << 88, no overflow).
// ROUND-13 STRUCTURE (best measured: 70 us, VGPR 16, occ ~61%) — r15's reg-array ILP
// variant cost occupancy (44 VGPR, 43%) and regressed; TLP is the latency hider here.

__global__ __launch_bounds__(256) void k_edge(const int* __restrict__ off,
                                              const int* __restrict__ csr,
                                              const float* __restrict__ as_,
                                              const float* __restrict__ ad_,
                                              const unsigned* __restrict__ hpb,
                                              const float* __restrict__ bg,
                                              const float* __restrict__ gamma,
                                              const float* __restrict__ beta,
                                              const float* __restrict__ rm,
                                              const float* __restrict__ rv,
                                              float* __restrict__ h,
                                              const int* __restrict__ batch,
                                              float* __restrict__ pooled) {
    __shared__ float plds[512];                     // per wave: 128 floats (2 nodes x 64)
    int tid = threadIdx.x;
    int lane = tid & 63;
    int n0 = __builtin_amdgcn_readfirstlane(blockIdx.x * 8 + (tid >> 6) * 2);  // exact grid
    int n1 = n0 + 1;
    int beg0 = off[n0], end0 = off[n0 + 1], end1 = off[n0 + 2];
    int beg1 = end0;                                // consecutive nodes share the boundary

    int hd = lane & 3, slot = lane >> 2;            // alpha role: edge slot x head
    float adv0 = ad_[n0 * NHEAD + hd];
    float adv1 = ad_[n1 * NHEAD + hd];
    const int hh = (lane < 48) ? (lane / 12) : 0;   // gather role: head of channel pair
    const bool gl = (lane < 48);
    const int wb = (tid & 192) * 2;                 // wave's plds region (w*128)

    float a00 = 0.f, a01 = 0.f, a10 = 0.f, a11 = 0.f, zA = 0.f, zB = 0.f;
    int ca = beg0, cb = beg1;
    while (ca < end0 || cb < end1) {
        int cntA = min(16, end0 - ca);              // wave-uniform chunk fills
        int cntB = min(16, end1 - cb);
        int sA = 0, sB = 0;
        if (cntA > 0) {
            int i = ca + slot, ii = min(i, end0 - 1);
            sA = csr[ii];
            float ev = as_[sA * NHEAD + hd] + adv0;
            ev = ev > 0.f ? ev : 0.2f * ev;
            float p = (i < end0) ? __expf(ev) : 0.f;
            zA += p;
            plds[wb + lane] = p;
        }
        if (cntB > 0) {
            int i = cb + slot, ii = min(i, end1 - 1);
            sB = csr[ii];
            float ev = as_[sB * NHEAD + hd] + adv1;
            ev = ev > 0.f ? ev : 0.2f * ev;
            float p = (i < end1) ? __expf(ev) : 0.f;
            zB += p;
            plds[wb + 64 + lane] = p;
        }
        if (cntA > 0) {
#pragma unroll
            for (int j = 0; j < 16; ++j) {
                if (j < cntA) {                     // wave-uniform guard: skip masked gathers
                    int sv = __builtin_amdgcn_readlane(sA, j * 4);
                    float al = plds[wb + j * 4 + hh];
                    if (gl) {
                        unsigned u = (hpb + (size_t)sv * (HIDD / 2))[lane];
                        a00 = fmaf(__uint_as_float(u << 16),         al, a00);
                        a01 = fmaf(__uint_as_float(u & 0xffff0000u), al, a01);
                    }
                }
            }
            ca += 16;
        }
        if (cntB > 0) {
#pragma unroll
            for (int j = 0; j < 16; ++j) {
                if (j < cntB) {
                    int sv = __builtin_amdgcn_readlane(sB, j * 4);
                    float al = plds[wb + 64 + j * 4 + hh];
                    if (gl) {
                        unsigned u = (hpb + (size_t)sv * (HIDD / 2))[lane];
                        a10 = fmaf(__uint_as_float(u << 16),         al, a10);
                        a11 = fmaf(__uint_as_float(u & 0xffff0000u), al, a11);
                    }
                }
            }
            cb += 16;
        }
    }
    // z totals per head for both nodes
#pragma unroll
    for (int o = 4; o < 64; o <<= 1) { zA += __shfl_xor(zA, o); zB += __shfl_xor(zB, o); }
    float za0 = rl_f(zA, 0), za1 = rl_f(zA, 1), za2 = rl_f(zA, 2), za3 = rl_f(zA, 3);
    float zb0 = rl_f(zB, 0), zb1 = rl_f(zB, 1), zb2 = rl_f(zB, 2), zb3 = rl_f(zB, 3);
    float zAl = (hh & 1) ? za1 : za0, zAh = (hh & 1) ? za3 : za2;
    float zBl = (hh & 1) ? zb1 : zb0, zBh = (hh & 1) ? zb3 : zb2;
    float zhA = (hh & 2) ? zAh : zAl;
    float zhB = (hh & 2) ? zBh : zBl;

    int g0 = batch[n0], g1 = batch[n1];             // uniform (s_load)
    if (gl) {
        float izA = 1.f / zhA, izB = 1.f / zhB;     // z > 0 guaranteed (self-loop)
        a00 *= izA; a01 *= izA; a10 *= izB; a11 *= izB;
        int ch0 = 2 * lane, ch1 = ch0 + 1;
        float hn00 = bnorm(a00, bg, rm, rv, gamma, beta, ch0);
        float hn01 = bnorm(a01, bg, rm, rv, gamma, beta, ch1);
        float hn10 = bnorm(a10, bg, rm, rv, gamma, beta, ch0);
        float hn11 = bnorm(a11, bg, rm, rv, gamma, beta, ch1);
        float2 hv0 = *(float2*)(h + (size_t)n0 * HIDD + ch0);
        float2 hv1 = *(float2*)(h + (size_t)n1 * HIDD + ch0);
        hv0.x += elu1(hn00); hv0.y += elu1(hn01);
        hv1.x += elu1(hn10); hv1.y += elu1(hn11);
        *(float2*)(h + (size_t)n0 * HIDD + ch0) = hv0;
        *(float2*)(h + (size_t)n1 * HIDD + ch0) = hv1;
        if (g0 == g1) {                             // merged pooled atomics (common: sorted batch)
            atomicAdd(&pooled[g0 * HIDD + ch0], hv0.x + hv1.x);
            atomicAdd(&pooled[g0 * HIDD + ch1], hv0.y + hv1.y);
        } else {
            atomicAdd(&pooled[g0 * HIDD + ch0], hv0.x);
            atomicAdd(&pooled[g0 * HIDD + ch1], hv0.y);
            atomicAdd(&pooled[g1 * HIDD + ch0], hv1.x);
            atomicAdd(&pooled[g1 * HIDD + ch1], hv1.y);
        }
    }
}

// ---------------- per-graph MLP head ----------------

__global__ __launch_bounds__(128) void k_head(const float* __restrict__ pooled,
                                              const float* __restrict__ Wjk, const float* __restrict__ bjk,
                                              const float* __restrict__ Wh1, const float* __restrict__ bh1,
                                              const float* __restrict__ Wh2, const float* __restrict__ bh2,
                                              float* __restrict__ out) {
    __shared__ float pin[NLAY * HIDD];
    __shared__ float z1[HIDD];
    __shared__ float z2[HIDD];
    int g = blockIdx.x, tid = threadIdx.x;
    for (int idx = tid; idx < NLAY * HIDD; idx += blockDim.x) {
        int l = idx / HIDD, c = idx % HIDD;
        pin[idx] = pooled[(size_t)l * NGRF * HIDD + (size_t)g * HIDD + c];
    }
    __syncthreads();
    for (int c = tid; c < HIDD; c += blockDim.x) {
        float a = bjk[c];
#pragma unroll 8
        for (int k = 0; k < NLAY * HIDD; ++k) a = fmaf(pin[k], Wjk[k * HIDD + c], a);
        z1[c] = elu1(a);
    }
    __syncthreads();
    for (int c = tid; c < HIDD; c += blockDim.x) {
        float a = bh1[c];
#pragma unroll 8
        for (int k = 0; k < HIDD; ++k) a = fmaf(z1[k], Wh1[k * HIDD + c], a);
        z2[c] = fmaxf(a, 0.f);
    }
    __syncthreads();
    if (tid < 64) {
        float a = 0.f;
        for (int k = tid; k < HIDD; k += 64) a = fmaf(z2[k], Wh2[k], a);
#pragma unroll
        for (int o = 32; o > 0; o >>= 1) a += __shfl_down(a, o);
        if (tid == 0) out[g] = a + bh2[0];
    }
}

extern "C" void kernel_launch(void* const* d_in, const int* in_sizes, int n_in,
                              void* d_out, int out_size, void* d_ws, size_t ws_size,
                              hipStream_t stream) {
    const float* x     = (const float*)d_in[0];
    const int*   ei    = (const int*)d_in[1];
    const int*   batch = (const int*)d_in[2];
    const float* W_in  = (const float*)d_in[3];
    const float* b_in  = (const float*)d_in[4];
    const float* Wg    = (const float*)d_in[5];
    const float* att_s = (const float*)d_in[6];
    const float* att_d = (const float*)d_in[7];
    const float* bg    = (const float*)d_in[8];
    const float* gamma = (const float*)d_in[9];
    const float* beta  = (const float*)d_in[10];
    const float* rm    = (const float*)d_in[11];
    const float* rv    = (const float*)d_in[12];
    const float* Wjk   = (const float*)d_in[13];
    const float* bjk   = (const float*)d_in[14];
    const float* Wh1   = (const float*)d_in[15];
    const float* bh1   = (const float*)d_in[16];
    const float* Wh2   = (const float*)d_in[17];
    const float* bh2   = (const float*)d_in[18];
    float* out = (float*)d_out;

    const int* S = ei;
    const int* Dd = ei + EDGES;

    // workspace layout
    float* ws = (float*)d_ws;
    float*    h      = ws;                               // N*96 f32
    float*    as_    = h    + (size_t)NODES * HIDD;      // N*4
    float*    ad_    = as_  + (size_t)NODES * NHEAD;     // N*4
    float*    pooled = ad_  + (size_t)NODES * NHEAD;     // L*G*96
    unsigned* hpb    = (unsigned*)(pooled + (size_t)NLAY * NGRF * HIDD); // N*48 (bf16x2)
    int*      off    = (int*)(hpb + (size_t)NODES * (HIDD / 2));  // N+2
    int*      cursor = off    + NODES + 2;               // N
    int*      csr    = cursor + NODES;                   // EP
    int*      cnt    = csr    + EP;                      // N
    int*      bsum   = cnt    + NODES;                   // NB

    hipMemsetAsync(cnt, 0, sizeof(int) * NODES, stream);

    const int TB = 256;
    int gE    = (EP + TB - 1) / TB;
    int gTile = (NODES + 63) / 64;    // 782 blocks, 64 nodes each
    int gEdge = NODES / 8;            // 6250 (exact: 8 nodes/block, 2 per wave)

    // CSR build (graph is identical across layers)
    k_count<<<gE, TB, 0, stream>>>(S, Dd, cnt);
    k_scan1<<<NB, 1024, 0, stream>>>(cnt, off, bsum);
    k_scan3m<<<NB, 1024, 0, stream>>>(off, bsum, cursor);
    k_scatter<<<gE, TB, 0, stream>>>(S, Dd, cursor, csr);

    // layer 0: fused input-proj + proj (also zeros pooled)
    k_in_proj_proj<<<gTile, TB, 0, stream>>>(x, W_in, b_in, Wg, att_s, att_d,
                                             h, hpb, as_, ad_, pooled);
    k_edge<<<gEdge, TB, 0, stream>>>(off, csr, as_, ad_, hpb,
                                     bg, gamma, beta, rm, rv, h, batch, pooled);

    for (int i = 1; i < NLAY; ++i) {
        k_proj<<<gTile, TB, 0, stream>>>(h, Wg + (size_t)i * HIDD * HIDD,
                                         att_s + i * NHEAD * CHD, att_d + i * NHEAD * CHD,
                                         hpb, as_, ad_);
        k_edge<<<gEdge, TB, 0, stream>>>(off, csr, as_, ad_, hpb,
                                         bg + i * HIDD, gamma + i * HIDD, beta + i * HIDD,
                                         rm + i * HIDD, rv + i * HIDD, h, batch,
                                         pooled + (size_t)i * NGRF * HIDD);
    }

    k_head<<<NGRF, 128, 0, stream>>>(pooled, Wjk, bjk, Wh1, bh1, Wh2, bh2, out);
}